// Round 1
// 143.375 us; speedup vs baseline: 1.0399x; 1.0399x over previous
//
#include <hip/hip_runtime.h>

// RGCN basis-decomposition layer, MI355X (gfx950).
//
// Algebra (torch-.view quirk folded out):
//   U[n][k*4+b] = sum_{j<8} h[n][k*8+j] * w_comp[j][b]     (fold, [N,128], bf16)
//   S[r][d]     = sum_{e: dst=d, et=r} U[src_e]            (bucketed aggregate)
//   out         = relu(sum_r S[r] @ Bv[r] + bias)          (bf16 MFMA GEMM, K=8*128)
//
// R8: per-(dst,relation) sub-buckets (SUBCAP=32, Poisson lambda=2/group):
//   - FILL atomics spread over 160K counters (was 20K): contention 16 -> 2.
//   - aggregate loses the readfirstlane/switch; acc[r] target is static.
//   - uint2 gathers: 32 lanes/row -> 2 edges per load instruction; phase A
//     issues all 8 relations' first-2-edge gathers up front (16-edge
//     capacity ~= avg degree), rare tails afterwards.
//   - half-wave shfl_xor(32) combine + uint2 store; S layout unchanged.
// R7: fusion reverted (R6: 70KB LDS -> 26% occ = 87us vs 56us split).

#define N_NODES  20000
#define N_EDGES  320000
#define IN_DIM   256
#define OUT_DIM  256
#define NUM_RELS 8
#define KDIM     128
#define M_PAD    20032          // 626 * 32
#define SUBCAP   32             // per-(dst,rel) capacity (lambda=2, P(>32)~1e-28)

#define FOLD_BLOCKS 2500        // N_NODES*32 / 256
#define FILL_BLOCKS 1250        // N_EDGES / 256
#define BP_BLOCKS   128         // 8ct*8r*8ks*64lane fragments / 256 thr

typedef __attribute__((ext_vector_type(8)))  short short8;
typedef __attribute__((ext_vector_type(16))) float float16v;

static __device__ __forceinline__ unsigned f2bf_rne(float x) {
    unsigned u = __float_as_uint(x);
    return (u + 0x7fffu + ((u >> 16) & 1u)) >> 16;
}

// ----------------------------------------------------------------- prep ----
// blockIdx [0, FOLD)           : fold h -> U (bf16)
// blockIdx [FOLD, FOLD+FILL)   : bucket-fill edges by (dst, rel)
// blockIdx [FOLD+FILL, ...+BP) : basis -> Bp (bf16, MFMA-fragment order)
__global__ __launch_bounds__(256)
void prep_kernel(const float* __restrict__ h, const float* __restrict__ w_comp,
                 unsigned short* __restrict__ U,
                 const int* __restrict__ src, const int* __restrict__ dst,
                 const int* __restrict__ et,
                 int* __restrict__ cnt2, int* __restrict__ bucket2,
                 const float* __restrict__ basis, unsigned short* __restrict__ Bp) {
    int b = blockIdx.x;
    int t = threadIdx.x;
    if (b < FOLD_BLOCKS) {
        // thread computes U[n][k*4 .. k*4+3]
        int gid = b * 256 + t;                 // over N_NODES*32
        int n = gid >> 5, k = gid & 31;
        const float* hp = h + (size_t)n * IN_DIM + k * 8;
        float4 h0 = *(const float4*)hp;
        float4 h1 = *(const float4*)(hp + 4);
        float hv[8] = {h0.x, h0.y, h0.z, h0.w, h1.x, h1.y, h1.z, h1.w};
        float a0 = 0.f, a1 = 0.f, a2 = 0.f, a3 = 0.f;
#pragma unroll
        for (int j = 0; j < 8; ++j) {
            float hj = hv[j];
            a0 += hj * w_comp[j * 4 + 0];
            a1 += hj * w_comp[j * 4 + 1];
            a2 += hj * w_comp[j * 4 + 2];
            a3 += hj * w_comp[j * 4 + 3];
        }
        uint2 p;
        p.x = f2bf_rne(a0) | (f2bf_rne(a1) << 16);
        p.y = f2bf_rne(a2) | (f2bf_rne(a3) << 16);
        *(uint2*)(U + ((size_t)n << 7) + k * 4) = p;
    } else if (b < FOLD_BLOCKS + FILL_BLOCKS) {
        int e = (b - FOLD_BLOCKS) * 256 + t;
        int g = dst[e] * 8 + et[e];            // (dst, rel) group
        int p = atomicAdd(&cnt2[g], 1);
        if (p < SUBCAP) bucket2[(g << 5) + p] = src[e];
    } else {
        // one B fragment (16B) per thread, MFMA fragment order:
        // Bp[((ct*8+r)*8+ks)*64+lane][j] =
        //   bf16(basis[(r*128+ks*16+(lane>>5)*8+j)*256 + ct*32+(lane&31)])
        int frag = (b - FOLD_BLOCKS - FILL_BLOCKS) * 256 + t;   // [0, 32768)
        int lane = frag & 63;
        int ks   = (frag >> 6) & 7;
        int r    = (frag >> 9) & 7;
        int ct   = frag >> 12;
        int o  = ct * 32 + (lane & 31);
        int kb = r * 128 + ks * 16 + (lane >> 5) * 8;
        const float* bsp = basis + (size_t)kb * 256 + o;
        unsigned v[8];
#pragma unroll
        for (int j = 0; j < 8; ++j) v[j] = f2bf_rne(bsp[(size_t)j * 256]);
        uint4 p;
        p.x = v[0] | (v[1] << 16);
        p.y = v[2] | (v[3] << 16);
        p.z = v[4] | (v[5] << 16);
        p.w = v[6] | (v[7] << 16);
        *(uint4*)(Bp + (size_t)frag * 8) = p;
    }
}

// ------------------------------------------------------------ aggregate ----
// One wave per dst node. Per-(dst,rel) sub-buckets: lanes 0-31 = edge slot 0,
// lanes 32-63 = edge slot 1; each lane covers 4 k-dims (uint2 = 4 bf16).
// Phase A issues all 8 relations' slot-{0,1} gathers before any consume;
// tails (counts > 2) mop up. Garbage slots masked &0x7fff stay in-workspace
// and are discarded by the (slot < count) predicate.
__global__ __launch_bounds__(256)
void aggregate_kernel(const unsigned short* __restrict__ U,
                      const int* __restrict__ cnt2,
                      const int* __restrict__ bucket2,
                      unsigned int* __restrict__ S) {  // S as uint (2 bf16)
    int wid  = threadIdx.x >> 6;
    int lane = threadIdx.x & 63;
    int half = lane >> 5;            // edge slot parity
    int l32  = lane & 31;            // dim group: dims [4*l32, 4*l32+4)
    int d = blockIdx.x * 4 + wid;    // < 20032

    float4 acc[NUM_RELS];
#pragma unroll
    for (int r = 0; r < NUM_RELS; ++r) acc[r] = make_float4(0.f, 0.f, 0.f, 0.f);

    if (d < N_NODES) {
        int base = d * 8;
        int4 ca = *(const int4*)(cnt2 + base);
        int4 cb = *(const int4*)(cnt2 + base + 4);
        int c[8] = {ca.x, ca.y, ca.z, ca.w, cb.x, cb.y, cb.z, cb.w};
#pragma unroll
        for (int r = 0; r < 8; ++r) if (c[r] > SUBCAP) c[r] = SUBCAP;

        // phase A: first 2 edges of every relation, all gathers in flight
        uint2 ga[8];
#pragma unroll
        for (int r = 0; r < 8; ++r) {
            int s = bucket2[((base + r) << 5) + half] & 0x7fff;
            ga[r] = *(const uint2*)(U + ((size_t)s << 7) + l32 * 4);
        }
#pragma unroll
        for (int r = 0; r < 8; ++r) {
            if (half < c[r]) {               // uniform per half-wave
                acc[r].x += __uint_as_float(ga[r].x << 16);
                acc[r].y += __uint_as_float(ga[r].x & 0xffff0000u);
                acc[r].z += __uint_as_float(ga[r].y << 16);
                acc[r].w += __uint_as_float(ga[r].y & 0xffff0000u);
            }
        }
        // tails: relations with count > 2 (expected ~1-2 rounds per node)
#pragma unroll
        for (int r = 0; r < 8; ++r) {
            for (int i = 2; i < c[r]; i += 2) {
                int s = bucket2[((base + r) << 5) + i + half] & 0x7fff;
                uint2 g = *(const uint2*)(U + ((size_t)s << 7) + l32 * 4);
                if (i + half < c[r]) {
                    acc[r].x += __uint_as_float(g.x << 16);
                    acc[r].y += __uint_as_float(g.x & 0xffff0000u);
                    acc[r].z += __uint_as_float(g.y << 16);
                    acc[r].w += __uint_as_float(g.y & 0xffff0000u);
                }
            }
        }
    }
    // combine the two edge-slot halves, then half-wave uint2 store
#pragma unroll
    for (int r = 0; r < NUM_RELS; ++r) {
        acc[r].x += __shfl_xor(acc[r].x, 32);
        acc[r].y += __shfl_xor(acc[r].y, 32);
        acc[r].z += __shfl_xor(acc[r].z, 32);
        acc[r].w += __shfl_xor(acc[r].w, 32);
    }
    if (half == 0) {
#pragma unroll
        for (int r = 0; r < NUM_RELS; ++r) {
            uint2 p;
            p.x = f2bf_rne(acc[r].x) | (f2bf_rne(acc[r].y) << 16);
            p.y = f2bf_rne(acc[r].z) | (f2bf_rne(acc[r].w) << 16);
            *(uint2*)(S + (((size_t)r * M_PAD + d) << 6) + l32 * 2) = p;
        }
    }
}

// ----------------------------------------------------------------- gemm ----
// out[n][o] = relu(sum_{r,k} S[r][n][k] * Bp-frag + bias[o])
// 512 thr = 8 waves; C tile 32 rows x 256 cols; wave w -> one 32x32 MFMA
// tile at cols w*32. Grid 626. A staged once via LDS (VGPR prefetch of the
// next relation); B fragments read coalesced from packed Bp (L2-resident).
__global__ __launch_bounds__(512)
void gemm_kernel(const unsigned short* __restrict__ S,
                 const unsigned short* __restrict__ Bp,
                 const float* __restrict__ bias,
                 float* __restrict__ out) {
    __shared__ unsigned short At[32][136];
    int t = threadIdx.x;
    int w = t >> 6, lane = t & 63;
    int ln = lane & 31, hi = lane >> 5;
    int n0 = blockIdx.x * 32;
    int c0 = w * 32;

    int srow = t >> 4, sq = t & 15;        // staging: 512 x 16B = 32 rows x 256B
    const unsigned short* sbase = S + (((size_t)n0 + srow) << 7) + sq * 8;
    uint4 pre = *(const uint4*)sbase;      // r=0 A-tile fragment

    float16v acc = {};

    for (int r = 0; r < NUM_RELS; ++r) {
        if (r > 0) __syncthreads();        // prev iter's LDS reads complete
        *(uint4*)&At[srow][sq * 8] = pre;
        __syncthreads();
        if (r + 1 < NUM_RELS)
            pre = *(const uint4*)(sbase + (((size_t)(r + 1) * M_PAD) << 7));
        // packed B: fragment base for (ct=w, r, ks), 1KB contiguous per wave
        const unsigned short* bpr = Bp + (((size_t)(w * 8 + r) * 8) << 9) + lane * 8;
#pragma unroll
        for (int ks = 0; ks < 8; ++ks) {
            short8 a  = *(const short8*)&At[ln][ks * 16 + hi * 8];
            short8 bo = *(const short8*)(bpr + (ks << 9));
            acc = __builtin_amdgcn_mfma_f32_32x32x16_bf16(a, bo, acc, 0, 0, 0);
        }
    }

    // epilogue: C/D layout col=lane&31, row=(reg&3)+8*(reg>>2)+4*(lane>>5)
    float bs = bias[c0 + ln];
#pragma unroll
    for (int reg = 0; reg < 16; ++reg) {
        int row = (reg & 3) + 8 * (reg >> 2) + 4 * hi;
        int n = n0 + row;
        if (n < N_NODES)
            out[(size_t)n * OUT_DIM + c0 + ln] = fmaxf(acc[reg] + bs, 0.f);
    }
}

// --------------------------------------------------------------- launch ----
extern "C" void kernel_launch(void* const* d_in, const int* in_sizes, int n_in,
                              void* d_out, int out_size, void* d_ws, size_t ws_size,
                              hipStream_t stream) {
    const float* h      = (const float*)d_in[0];
    const float* basis  = (const float*)d_in[1];
    const float* w_comp = (const float*)d_in[2];
    const float* bias   = (const float*)d_in[3];
    const int*   src    = (const int*)d_in[4];
    const int*   dst    = (const int*)d_in[5];
    const int*   etype  = (const int*)d_in[6];
    float*       out    = (float*)d_out;

    char* ws = (char*)d_ws;
    size_t off = 0;
    unsigned short* U   = (unsigned short*)(ws + off); off += (size_t)N_NODES * KDIM * 2;          // 5.12 MB
    unsigned int*   S   = (unsigned int*)(ws + off);   off += (size_t)NUM_RELS * M_PAD * KDIM * 2; // 41.0 MB
    unsigned short* Bp  = (unsigned short*)(ws + off); off += (size_t)8 * 8 * 8 * 64 * 8 * 2;      // 0.52 MB
    int* cnt2    = (int*)(ws + off); off += (size_t)M_PAD * 8 * 4;                                 // 0.64 MB
    int* bucket2 = (int*)(ws + off); off += ((size_t)M_PAD * 8 * SUBCAP + 64) * 4;                 // 20.5 MB (+slack)

    hipMemsetAsync(cnt2, 0, (size_t)N_NODES * 8 * 4, stream);

    prep_kernel<<<FOLD_BLOCKS + FILL_BLOCKS + BP_BLOCKS, 256, 0, stream>>>(
        h, w_comp, U, src, dst, etype, cnt2, bucket2, basis, Bp);

    aggregate_kernel<<<M_PAD / 4, 256, 0, stream>>>(U, cnt2, bucket2, S);

    gemm_kernel<<<M_PAD / 32, 512, 0, stream>>>((const unsigned short*)S, Bp, bias, out);
}